// Round 10
// baseline (433.810 us; speedup 1.0000x reference)
//
#include <hip/hip_runtime.h>
#include <hip/hip_bf16.h>

// QRNN fo-pool: T=65536, E=512, H=512 (kernel_size=2)
// gates[T,1536] = concat(x, shift(x)) @ W + b ; z=tanh, f,o=sigmoid
// c_t = f_t c_{t-1} + (1-f_t) z_t ; h_t = o_t c_t
// out = [hiddens (T*512) | h_last (512) | c_last (512)]  (f32)

#define T_LEN 65536
#define H3    1536
#define LC    64
#define NCHUNK 1024

typedef float f32x4 __attribute__((ext_vector_type(4)));
typedef short bf16x8 __attribute__((ext_vector_type(8)));

__device__ __forceinline__ unsigned short f2bf(float f) {
    unsigned int x = __builtin_bit_cast(unsigned int, f);
    x += 0x7fffu + ((x >> 16) & 1u);
    return (unsigned short)(x >> 16);
}
__device__ __forceinline__ float bf2f(unsigned short u) {
    return __builtin_bit_cast(float, ((unsigned int)u) << 16);
}
// fast sigmoid/tanh: v_exp_f32 (exp2) + v_rcp_f32, ~1ulp each — far below bf16 grid
__device__ __forceinline__ float fsig(float x) {
    return __builtin_amdgcn_rcpf(1.f + __builtin_amdgcn_exp2f(-1.44269504f * x));
}
__device__ __forceinline__ float ftanh(float x) {
    return 2.f * __builtin_amdgcn_rcpf(1.f + __builtin_amdgcn_exp2f(-2.88539008f * x)) - 1.f;
}

__device__ __forceinline__ void gload_lds16(const void* g, void* l) {
    __builtin_amdgcn_global_load_lds((const __attribute__((address_space(1))) void*)g,
                                     (__attribute__((address_space(3))) void*)l, 16, 0, 0);
}

// hardware cvt (RNE), pairs fuse to v_cvt_pk_bf16_f32
__device__ __forceinline__ bf16x8 pack8(float4 a, float4 b) {
    union { bf16x8 v; unsigned short u[8]; } r;
    r.u[0] = __builtin_bit_cast(unsigned short, __float2bfloat16(a.x));
    r.u[1] = __builtin_bit_cast(unsigned short, __float2bfloat16(a.y));
    r.u[2] = __builtin_bit_cast(unsigned short, __float2bfloat16(a.z));
    r.u[3] = __builtin_bit_cast(unsigned short, __float2bfloat16(a.w));
    r.u[4] = __builtin_bit_cast(unsigned short, __float2bfloat16(b.x));
    r.u[5] = __builtin_bit_cast(unsigned short, __float2bfloat16(b.y));
    r.u[6] = __builtin_bit_cast(unsigned short, __float2bfloat16(b.z));
    r.u[7] = __builtin_bit_cast(unsigned short, __float2bfloat16(b.w));
    return r.v;
}

#define VM4()   asm volatile("s_waitcnt vmcnt(4)" ::: "memory")
#define VM0()   asm volatile("s_waitcnt vmcnt(0)" ::: "memory")
#define LGKM0() asm volatile("s_waitcnt lgkmcnt(0)" ::: "memory")
#define BARX()  __builtin_amdgcn_s_barrier()
#define ORD()   asm volatile("" ::: "memory")   // compiler-only order pin

// ---- prep: W [1024,1536] f32 -> Wt [1536,1024] bf16 ----------------------
__global__ void prep_w(const float* __restrict__ W, unsigned short* __restrict__ Wt) {
    const int n_el = 1024 * H3;
    for (int i = blockIdx.x * blockDim.x + threadIdx.x; i < n_el;
         i += gridDim.x * blockDim.x) {
        const int k = i / H3, n = i - k * H3;
        Wt[n * 1024 + k] = f2bf(W[i]);
    }
}

// ---- GEMM: 128Mx256N tile, BK=32, 4 waves of 64x128, depth-2 pipeline ----
// A is fused-converted from x (f32) via reg-staging (T14): iter t issues
// A(t+2)->regs (4x float4), gates vmcnt(4) [waits A(t+1)-regs + B(t+1)-LDS;
// A(t+2)'s 4 loads stay in flight ~2 iters], then cvt+ds_write A(t+1) with
// the SAME XOR involution the read uses (16B-slot s' = s ^ ((row>>1)&3)).
// B keeps global_load_lds (linear dest + pre-swizzled source, rule #21).
// A[t][k]: k<512 -> x[t][k]; k>=512 -> x[t-1][k-512] (zeros for t==0),
// handled by a single running pointer with a -992 jump after K-tile 15 and
// an exec-masked zero for the 4 threads that would read row -1.
// LDS: A[2][128*32] 16KB + B[2][256*32] 32KB = 48 KiB.
__global__ __launch_bounds__(256, 2) void gemm_gates(
    const float* __restrict__ x,
    const unsigned short* __restrict__ Wt,
    const float* __restrict__ bias,
    unsigned short* __restrict__ zfo)
{
    __shared__ unsigned short Alds[2][128 * 32];
    __shared__ unsigned short Blds[2][256 * 32];

    const int tid  = threadIdx.x;
    const int lane = tid & 63;
    const int w    = tid >> 6;           // wave 0..3
    const int wm   = w >> 1, wn = w & 1; // 2x2 wave grid, each 64M x 128N

    // XCD-chunked swizzle (T1): 3072 blocks, 384/XCD; the 6 blocks sharing
    // an A-panel land consecutively on ONE XCD; B (3 MB) L2-resident.
    const int flat = blockIdx.y * gridDim.x + blockIdx.x;   // 0..3071
    const int idx  = (flat & 7) * 384 + (flat >> 3);
    const int nb   = (idx % 6) * 256;                       // N base (0..1280)
    const long long t0 = (long long)(idx / 6) * 128;        // M base (time rows)

    // staging geometry: lane -> (row = lane>>2 within 16-row group, 16B slot = lane&3)
    const int srow_l = lane >> 2;                               // 0..15
    const int aRow   = w * 16 + srow_l;                         // 0..63 (part0; part1 = +64)
    const bool azero = (t0 == 0) && (aRow == 0);                // would read row -1 at s>=16
    const int scol   = (((lane & 3) ^ ((lane >> 3) & 3)) * 8);  // B pre-swizzled source col

    // A source pointer: off(s) = 32*s (s<16) | 32*s - 1024 (s>=16); wrap -992 after s==15
    const float* gA = x + (t0 + aRow) * 512 + (lane & 3) * 8;
    const unsigned short* gB = Wt + (long long)(nb + aRow) * 1024 + scol;

    auto issueA = [&](float4* r, int s) {
        if (azero && s >= 16) {
            r[0] = float4{0.f, 0.f, 0.f, 0.f};
            r[1] = float4{0.f, 0.f, 0.f, 0.f};
        } else {
            r[0] = *reinterpret_cast<const float4*>(gA);
            r[1] = *reinterpret_cast<const float4*>(gA + 4);
        }
        r[2] = *reinterpret_cast<const float4*>(gA + 64 * 512);
        r[3] = *reinterpret_cast<const float4*>(gA + 64 * 512 + 4);
    };
    auto writeA = [&](unsigned short* Al, const float4* r) {
        const int sw = (lane & 3) ^ ((srow_l >> 1) & 3);        // same involution as read
        unsigned short* a0 = Al + aRow * 32 + sw * 8;
        *reinterpret_cast<bf16x8*>(a0)           = pack8(r[0], r[1]);
        *reinterpret_cast<bf16x8*>(a0 + 64 * 32) = pack8(r[2], r[3]);  // row+64: same swz
    };
    auto stageB = [&](unsigned short* Bl) {
        gload_lds16(gB,              Bl + (w * 16) * 32);
        gload_lds16(gB + 64 * 1024,  Bl + (64 + w * 16) * 32);
        gload_lds16(gB + 128 * 1024, Bl + (128 + w * 16) * 32);
        gload_lds16(gB + 192 * 1024, Bl + (192 + w * 16) * 32);
    };

    // fragment read geometry (unchanged from R7)
    const int arow  = lane & 15;
    const int swzco = (((lane >> 4) ^ ((arow >> 1) & 3)) * 8);

    f32x4 acc[4][8] = {};

    auto compute = [&](const unsigned short* Al, const unsigned short* Bl) {
        bf16x8 af[4], bfr[8];
        #pragma unroll
        for (int m = 0; m < 4; ++m)
            af[m] = *reinterpret_cast<const bf16x8*>(Al + (wm * 64 + m * 16 + arow) * 32 + swzco);
        #pragma unroll
        for (int n = 0; n < 8; ++n)
            bfr[n] = *reinterpret_cast<const bf16x8*>(Bl + (wn * 128 + n * 16 + arow) * 32 + swzco);
        #pragma unroll
        for (int n = 0; n < 8; ++n)
            #pragma unroll
            for (int m = 0; m < 4; ++m)
                acc[m][n] = __builtin_amdgcn_mfma_f32_16x16x32_bf16(af[m], bfr[n], acc[m][n], 0, 0, 0);
    };

    float4 rP[4], rQ[4];

    // prologue: A(0)->rP, B(0)->LDS, A(1)->rQ; vmcnt(4) waits A(0)+B(0),
    // A(1) flies; write A(0); barrier.
    issueA(rP, 0); gA += 32;
    ORD();
    stageB(Blds[0]); gB += 32;
    ORD();
    issueA(rQ, 1); gA += 32;
    VM4();
    writeA(Alds[0], rP);
    LGKM0(); BARX();

    // main loop, pairs tp = 0,2,...,28 (buffer/reg roles compile-time)
    for (int tp = 0; tp < 30; tp += 2) {
        {   // t = tp (even): B(t+1)->Bbuf1, A(t+2)->rP, compute(Abuf0,Bbuf0)
            stageB(Blds[1]); gB += 32;
            ORD();
            issueA(rP, tp + 2); gA += 32;          // tp+2 even, never ==15
            compute(Alds[0], Blds[0]);
            VM4();                                  // A(t+1)+B(t+1) landed; A(t+2) flies
            writeA(Alds[1], rQ);                    // A(t+1) -> Abuf1
            LGKM0(); BARX();
        }
        {   // t = tp+1 (odd): B(t+1)->Bbuf0, A(t+2)->rQ, compute(Abuf1,Bbuf1)
            stageB(Blds[0]); gB += 32;
            ORD();
            issueA(rQ, tp + 3);
            gA += (tp == 12) ? -992 : 32;           // wrap after issuing s==15
            compute(Alds[1], Blds[1]);
            VM4();
            writeA(Alds[0], rP);                    // A(t+2... = tp+2) -> Abuf0
            LGKM0(); BARX();
        }
    }
    // tail: t=30: B(31)->Bbuf1; compute(Abuf0,Bbuf0); drain; write A(31)
    stageB(Blds[1]);
    compute(Alds[0], Blds[0]);
    VM0();
    writeA(Alds[1], rQ);
    LGKM0(); BARX();
    compute(Alds[1], Blds[1]);                      // t=31

    // epilogue: bias + activation. nb multiple of 256, class width 512 ->
    // single class per block: cls = nb>>9 (0=z tanh, 1=f, 2=o sigmoid).
    const int cls = nb >> 9;
    #pragma unroll
    for (int n = 0; n < 8; ++n) {
        const int col = nb + wn * 128 + n * 16 + arow;
        const float bn_ = bias[col];
        #pragma unroll
        for (int m = 0; m < 4; ++m) {
            const long long row0 = t0 + wm * 64 + m * 16 + (lane >> 4) * 4;
            #pragma unroll
            for (int j = 0; j < 4; ++j) {
                float v = acc[m][n][j] + bn_;
                v = (cls == 0) ? ftanh(v) : fsig(v);
                zfo[(row0 + j) * H3 + col] = f2bf(v);
            }
        }
    }
}

// ---- scan pass 1: per-chunk local scan (c_init=0) + product of f ---------
__global__ void scan_pass1(const unsigned short* __restrict__ zfo,
                           float* __restrict__ P, float* __restrict__ L) {
    const int chunk = blockIdx.x;
    const int c4    = threadIdx.x;           // 0..127
    const unsigned short* base = zfo + (long long)chunk * LC * H3 + c4 * 4;
    float c[4] = {0.f, 0.f, 0.f, 0.f};
    float p[4] = {1.f, 1.f, 1.f, 1.f};
    for (int t = 0; t < LC; ++t) {
        const unsigned short* row = base + t * H3;
        const ushort4 uz = *reinterpret_cast<const ushort4*>(row);
        const ushort4 uf = *reinterpret_cast<const ushort4*>(row + 512);
        const float z[4] = {bf2f(uz.x), bf2f(uz.y), bf2f(uz.z), bf2f(uz.w)};
        const float f[4] = {bf2f(uf.x), bf2f(uf.y), bf2f(uf.z), bf2f(uf.w)};
        #pragma unroll
        for (int j = 0; j < 4; ++j) {
            c[j] = fmaf(f[j], c[j] - z[j], z[j]);   // f*c + (1-f)*z
            p[j] *= f[j];
        }
    }
    #pragma unroll
    for (int j = 0; j < 4; ++j) {
        P[chunk * 512 + c4 * 4 + j] = p[j];
        L[chunk * 512 + c4 * 4 + j] = c[j];
    }
}

// ---- scan pass 2: parallel affine-composition scan over chunks -----------
__global__ __launch_bounds__(1024) void scan_pass2(
    const float* __restrict__ P, const float* __restrict__ L,
    float* __restrict__ carry, float* __restrict__ out) {
    const int ch = blockIdx.x;
    const int k  = threadIdx.x;
    __shared__ float sP[1024], sL[1024];
    float p = P[k * 512 + ch];
    float l = L[k * 512 + ch];
    sP[k] = p; sL[k] = l;
    __syncthreads();
    for (int d = 1; d < 1024; d <<= 1) {
        float pp = 1.f, ll = 0.f;
        if (k >= d) { pp = sP[k - d]; ll = sL[k - d]; }
        __syncthreads();
        l = fmaf(p, ll, l);
        p = p * pp;
        sP[k] = p; sL[k] = l;
        __syncthreads();
    }
    carry[k * 512 + ch] = (k == 0) ? 0.f : sL[k - 1];
    if (k == 1023) out[(long long)T_LEN * 512 + 512 + ch] = l;   // cells[-1]
}

// ---- scan pass 3: replay with carry-in, write h = o*c (float4 stores) ----
__global__ void scan_pass3(const unsigned short* __restrict__ zfo,
                           const float* __restrict__ carry,
                           float* __restrict__ out) {
    const int chunk = blockIdx.x;
    const int c4    = threadIdx.x;           // 0..127
    const unsigned short* base = zfo + (long long)chunk * LC * H3 + c4 * 4;
    float c[4], h[4] = {0.f, 0.f, 0.f, 0.f};
    #pragma unroll
    for (int j = 0; j < 4; ++j) c[j] = carry[chunk * 512 + c4 * 4 + j];
    float4* outp = reinterpret_cast<float4*>(out + (long long)chunk * LC * 512) + c4;
    for (int t = 0; t < LC; ++t) {
        const unsigned short* row = base + t * H3;
        const ushort4 uz = *reinterpret_cast<const ushort4*>(row);
        const ushort4 uf = *reinterpret_cast<const ushort4*>(row + 512);
        const ushort4 uo = *reinterpret_cast<const ushort4*>(row + 1024);
        const float z[4] = {bf2f(uz.x), bf2f(uz.y), bf2f(uz.z), bf2f(uz.w)};
        const float f[4] = {bf2f(uf.x), bf2f(uf.y), bf2f(uf.z), bf2f(uf.w)};
        const float o[4] = {bf2f(uo.x), bf2f(uo.y), bf2f(uo.z), bf2f(uo.w)};
        #pragma unroll
        for (int j = 0; j < 4; ++j) {
            c[j] = fmaf(f[j], c[j] - z[j], z[j]);
            h[j] = o[j] * c[j];
        }
        float4 hv; hv.x = h[0]; hv.y = h[1]; hv.z = h[2]; hv.w = h[3];
        outp[t * 128] = hv;
    }
    if (chunk == NCHUNK - 1) {
        #pragma unroll
        for (int j = 0; j < 4; ++j)
            out[(long long)T_LEN * 512 + c4 * 4 + j] = h[j];     // hiddens[-1]
    }
}

extern "C" void kernel_launch(void* const* d_in, const int* in_sizes, int n_in,
                              void* d_out, int out_size, void* d_ws, size_t ws_size,
                              hipStream_t stream) {
    const float* x = (const float*)d_in[0];   // [65536, 512]
    const float* W = (const float*)d_in[1];   // [1024, 1536]
    const float* b = (const float*)d_in[2];   // [1536]
    float* out = (float*)d_out;

    char* ws = (char*)d_ws;
    unsigned short* Wt  = (unsigned short*)(ws + 67110912LL);    // 3,145,728 B
    unsigned short* zfo = (unsigned short*)(ws + 70256640LL);    // 201,326,592 B
    float* P     = (float*)(ws);                                 // 2 MiB each
    float* L     = (float*)(ws + 4194304LL);
    float* carry = (float*)(ws + 8388608LL);

    prep_w<<<768, 256, 0, stream>>>(W, Wt);

    dim3 gg(H3 / 256, T_LEN / 128, 1);     // 6 x 512 = 3072 blocks
    gemm_gates<<<gg, 256, 0, stream>>>(x, Wt, b, zfo);

    scan_pass1<<<NCHUNK, 128, 0, stream>>>(zfo, P, L);
    scan_pass2<<<512, 1024, 0, stream>>>(P, L, carry, out);
    scan_pass3<<<NCHUNK, 128, 0, stream>>>(zfo, carry, out);
}